// Round 1
// baseline (527.972 us; speedup 1.0000x reference)
//
#include <hip/hip_runtime.h>
#include <hip/hip_bf16.h>
#include <stdint.h>

// ---------------------------------------------------------------------------
// LBConv: y = fc(relu(conv3x3_ternary(x))) + b
//   x        : [32][256][56][56] f32
//   binary_w : [512][256][3][3]  f32 (ternary)
//   fc_w     : [256][512]        f32
//   fc_b     : [256]             f32
//   out      : [32][256][56][56] f32
//
// Strategy: bf16 MFMA implicit GEMM. W padded to 64 (garbage cols masked),
// cin split into 2 groups of 128 so each (tap, cg) K-tile is one contiguous
// 32KB chunk -> global_load_lds width=16 staging. Inner layout
// [khi16][w64][klo8] makes ds_read_b128 fragment reads bank-conflict-free.
// ---------------------------------------------------------------------------

typedef __attribute__((ext_vector_type(8))) short short8;
typedef __attribute__((ext_vector_type(4))) float floatx4;

#define ROWE 8192            // elems per padded row per (b,cg): 16*64*8
#define PLANE (58*ROWE)      // per (b,cg) plane
#define NT_PER_B 28          // 3584/128

// workspace byte offsets
#define OFF_WP  0            // 9*2*512*128*2        = 2,359,296
#define OFF_A2  2359296      // 4*2*128*128*2        =   262,144
#define OFF_XP  2621440      // 64*58*8192*2         = 60,817,408 (+slack)
#define OFF_Y   63439872     // 896*4*16384*2        = 117,440,512
// total required ws: 180,880,384 bytes (~173 MB)

__device__ static inline void async16(const void* gptr, void* lptr) {
  __builtin_amdgcn_global_load_lds(
      (const __attribute__((address_space(1))) void*)gptr,
      (__attribute__((address_space(3))) void*)lptr,
      16, 0, 0);
}

__device__ static inline unsigned short f2bf(float x) {
  __hip_bfloat16 h = __float2bfloat16(x);
  return *reinterpret_cast<unsigned short*>(&h);
}

// ---------------- prep: x (NCHW f32) -> Xp[b*2+cg][h'58][khi16][w'64][klo8] bf16
__global__ void k_xprep(const float* __restrict__ x, __hip_bfloat16* __restrict__ Xp) {
  const int idx = blockIdx.x * 256 + threadIdx.x;        // < 30,408,704 exact
  const int klo = idx & 7;
  const int wq  = (idx >> 3) & 63;
  const int khi = (idx >> 9) & 15;
  const int t2  = idx >> 13;                             // bc*58 + hp
  const int hp  = t2 % 58;
  const int bc  = t2 / 58;
  const int b   = bc >> 1;
  const int cin = ((bc & 1) << 7) + (khi << 3) + klo;
  const int h = hp - 1, w = wq - 1;
  float v = 0.f;
  if ((unsigned)h < 56u && (unsigned)w < 56u)
    v = x[((b * 256 + cin) * 56 + h) * 56 + w];
  Xp[idx] = __float2bfloat16(v);
}

// ---------------- prep: binary_w -> Wp[tap9][cg2][cmblk4][cmh2][khi16][cml64][klo8]
__global__ void k_wprep(const float* __restrict__ bw, __hip_bfloat16* __restrict__ Wp) {
  const int idx = blockIdx.x * 256 + threadIdx.x;        // < 1,179,648 exact
  const int klo = idx & 7;
  const int cml = (idx >> 3) & 63;
  const int khi = (idx >> 9) & 15;
  const int cmh = (idx >> 13) & 1;
  const int rest = idx >> 14;                            // (tap*2+cg)*4 + cmblk
  const int cmblk = rest & 3;
  const int tcg = rest >> 2;
  const int cg  = tcg & 1;
  const int tap = tcg >> 1;
  const int kh = tap / 3, kw = tap - kh * 3;
  const int cm  = (cmblk << 7) + (cmh << 6) + cml;
  const int cin = (cg << 7) + (khi << 3) + klo;
  Wp[idx] = __float2bfloat16(bw[((cm * 256 + cin) * 3 + kh) * 3 + kw]);
}

// ---------------- prep: fc_w -> A2[cg4][mtile2][ch2][khi16][cl64][klo8]
__global__ void k_a2prep(const float* __restrict__ fw, __hip_bfloat16* __restrict__ A2) {
  const int idx = blockIdx.x * 256 + threadIdx.x;        // < 131,072 exact
  const int klo = idx & 7;
  const int cl  = (idx >> 3) & 63;
  const int khi = (idx >> 9) & 15;
  const int ch  = (idx >> 13) & 1;
  const int rest = idx >> 14;                            // cg*2 + mtile
  const int mtile = rest & 1;
  const int cg = rest >> 1;
  const int cout = (mtile << 7) + (ch << 6) + cl;
  const int cm   = (cg << 7) + (khi << 3) + klo;
  A2[idx] = __float2bfloat16(fw[cout * 512 + cm]);
}

// ---------------- conv1: Y[ntile][cmblk][r2][khi16][w64][klo8] = relu(W*Xp)
__global__ __launch_bounds__(256, 2) void k_conv1(
    const __hip_bfloat16* __restrict__ Xp, const __hip_bfloat16* __restrict__ Wp,
    __hip_bfloat16* __restrict__ Y) {
  __shared__ short8 lds_raw[4096];                       // 64KB: A[0,32K) B[32K,64K)
  char* lds = (char*)lds_raw;
  const int tid  = threadIdx.x;
  const int lane = tid & 63;
  const int wv   = tid >> 6;
  const int wm   = wv >> 1, wn = wv & 1;
  const int l15  = lane & 15;
  const int quad = lane >> 4;
  const int cmblk = blockIdx.x;                          // 0..3
  const int ntile = blockIdx.y;                          // 0..895
  const int b  = ntile / NT_PER_B;
  const int h0 = (ntile % NT_PER_B) * 2;

  floatx4 acc[4][4];
#pragma unroll
  for (int i = 0; i < 4; i++)
#pragma unroll
    for (int j = 0; j < 4; j++) acc[i][j] = (floatx4){0.f, 0.f, 0.f, 0.f};

  for (int t = 0; t < 18; ++t) {
    const int tap = t >> 1;
    const int cg  = t & 1;
    const int kh = tap / 3, kw = tap - kh * 3;
    const size_t a_base = (size_t)((tap * 2 + cg) * 4 + cmblk) * 16384;
    const size_t b_base = (size_t)((b * 2 + cg) * 58 + (h0 + kh)) * ROWE + kw * 8;
    __syncthreads();                                     // prev compute done
    const char* gA = (const char*)(Wp + a_base) + wv * 8192 + lane * 16;
    const char* gB = (const char*)(Xp + b_base) + wv * 8192 + lane * 16;
    char* lA = lds + wv * 8192;
    char* lB = lds + 32768 + wv * 8192;
#pragma unroll
    for (int c = 0; c < 8; ++c) {
      async16(gA + c * 1024, lA + c * 1024);
      async16(gB + c * 1024, lB + c * 1024);
    }
    __syncthreads();                                     // staging visible
#pragma unroll
    for (int kk = 0; kk < 4; ++kk) {
      short8 af[4], bf[4];
#pragma unroll
      for (int mi = 0; mi < 4; ++mi) {
        const int m = wm * 64 + mi * 16 + l15;
        af[mi] = *(const short8*)(lds + ((m >> 6) * 16 + kk * 4 + quad) * 1024 + (m & 63) * 16);
      }
#pragma unroll
      for (int ni = 0; ni < 4; ++ni) {
        const int n = wn * 64 + ni * 16 + l15;
        bf[ni] = *(const short8*)(lds + 32768 + ((n >> 6) * 16 + kk * 4 + quad) * 1024 + (n & 63) * 16);
      }
#pragma unroll
      for (int mi = 0; mi < 4; ++mi)
#pragma unroll
        for (int ni = 0; ni < 4; ++ni)
          acc[mi][ni] = __builtin_amdgcn_mfma_f32_16x16x32_bf16(af[mi], bf[ni], acc[mi][ni], 0, 0, 0);
    }
  }

  // epilogue: relu -> bf16, Y chunk (ntile, cmblk) layout [r2][khi16][w64][klo8]
  const size_t ybase = ((size_t)ntile * 4 + cmblk) * 16384;
#pragma unroll
  for (int mi = 0; mi < 4; ++mi) {
    const int cml  = wm * 64 + mi * 16 + quad * 4;       // + reg r
    const int khi  = cml >> 3;
    const int klo0 = cml & 7;                            // 0 or 4
#pragma unroll
    for (int ni = 0; ni < 4; ++ni) {
      const int n = wn * 64 + ni * 16 + l15;
      const int r = n >> 6, w = n & 63;
      floatx4 f = acc[mi][ni];
      unsigned lo = (unsigned)f2bf(fmaxf(f[0], 0.f)) | ((unsigned)f2bf(fmaxf(f[1], 0.f)) << 16);
      unsigned hi = (unsigned)f2bf(fmaxf(f[2], 0.f)) | ((unsigned)f2bf(fmaxf(f[3], 0.f)) << 16);
      uint2 pk = make_uint2(lo, hi);
      *(uint2*)((char*)Y + (ybase + (size_t)r * 8192 + khi * 512 + w * 8 + klo0) * 2) = pk;
    }
  }
}

// ---------------- conv2: out = fc_w * Y + b, mask w<56, store NCHW f32
__global__ __launch_bounds__(256, 2) void k_conv2(
    const __hip_bfloat16* __restrict__ Y, const __hip_bfloat16* __restrict__ A2,
    const float* __restrict__ fcb, float* __restrict__ out) {
  __shared__ short8 lds_raw[4096];
  char* lds = (char*)lds_raw;
  const int tid  = threadIdx.x;
  const int lane = tid & 63;
  const int wv   = tid >> 6;
  const int wm   = wv >> 1, wn = wv & 1;
  const int l15  = lane & 15;
  const int quad = lane >> 4;
  const int mtile = blockIdx.x;                          // 0..1
  const int rp    = blockIdx.y;                          // 0..895

  floatx4 acc[4][4];
#pragma unroll
  for (int i = 0; i < 4; i++)
#pragma unroll
    for (int j = 0; j < 4; j++) acc[i][j] = (floatx4){0.f, 0.f, 0.f, 0.f};

  for (int cg = 0; cg < 4; ++cg) {
    const size_t a_base = (size_t)(cg * 2 + mtile) * 16384;
    const size_t b_base = (size_t)(rp * 4 + cg) * 16384;
    __syncthreads();
    const char* gA = (const char*)(A2 + a_base) + wv * 8192 + lane * 16;
    const char* gB = (const char*)(Y + b_base) + wv * 8192 + lane * 16;
    char* lA = lds + wv * 8192;
    char* lB = lds + 32768 + wv * 8192;
#pragma unroll
    for (int c = 0; c < 8; ++c) {
      async16(gA + c * 1024, lA + c * 1024);
      async16(gB + c * 1024, lB + c * 1024);
    }
    __syncthreads();
#pragma unroll
    for (int kk = 0; kk < 4; ++kk) {
      short8 af[4], bf[4];
#pragma unroll
      for (int mi = 0; mi < 4; ++mi) {
        const int m = wm * 64 + mi * 16 + l15;
        af[mi] = *(const short8*)(lds + ((m >> 6) * 16 + kk * 4 + quad) * 1024 + (m & 63) * 16);
      }
#pragma unroll
      for (int ni = 0; ni < 4; ++ni) {
        const int n = wn * 64 + ni * 16 + l15;
        bf[ni] = *(const short8*)(lds + 32768 + ((n >> 6) * 16 + kk * 4 + quad) * 1024 + (n & 63) * 16);
      }
#pragma unroll
      for (int mi = 0; mi < 4; ++mi)
#pragma unroll
        for (int ni = 0; ni < 4; ++ni)
          acc[mi][ni] = __builtin_amdgcn_mfma_f32_16x16x32_bf16(af[mi], bf[ni], acc[mi][ni], 0, 0, 0);
    }
  }

  const int b   = rp / NT_PER_B;
  const int nb0 = (rp % NT_PER_B) * 128;
#pragma unroll
  for (int mi = 0; mi < 4; ++mi) {
    const int co = mtile * 128 + wm * 64 + mi * 16 + quad * 4;  // + reg r
#pragma unroll
    for (int ni = 0; ni < 4; ++ni) {
      const int n = wn * 64 + ni * 16 + l15;
      const int w = n & 63;
      if (w < 56) {
        const int nb = nb0 + n;
        const int h  = nb >> 6;
        floatx4 f = acc[mi][ni];
        const size_t base = (size_t)(b * 256 + co) * 3136 + h * 56 + w;
#pragma unroll
        for (int r = 0; r < 4; ++r)
          out[base + (size_t)r * 3136] = f[r] + fcb[co + r];
      }
    }
  }
}

extern "C" void kernel_launch(void* const* d_in, const int* in_sizes, int n_in,
                              void* d_out, int out_size, void* d_ws, size_t ws_size,
                              hipStream_t stream) {
  const float* x  = (const float*)d_in[0];
  const float* bw = (const float*)d_in[1];
  const float* fw = (const float*)d_in[2];
  const float* fb = (const float*)d_in[3];
  float* out = (float*)d_out;
  char* ws = (char*)d_ws;

  __hip_bfloat16* Wp = (__hip_bfloat16*)(ws + OFF_WP);
  __hip_bfloat16* A2 = (__hip_bfloat16*)(ws + OFF_A2);
  __hip_bfloat16* Xp = (__hip_bfloat16*)(ws + OFF_XP);
  __hip_bfloat16* Y  = (__hip_bfloat16*)(ws + OFF_Y);

  k_wprep<<<dim3(4608), dim3(256), 0, stream>>>(bw, Wp);
  k_a2prep<<<dim3(512), dim3(256), 0, stream>>>(fw, A2);
  k_xprep<<<dim3(118784), dim3(256), 0, stream>>>(x, Xp);
  k_conv1<<<dim3(4, 896), dim3(256), 0, stream>>>(Xp, Wp, Y);
  k_conv2<<<dim3(2, 896), dim3(256), 0, stream>>>(Y, A2, fb, out);
}

// Round 2
// 474.334 us; speedup vs baseline: 1.1131x; 1.1131x over previous
//
#include <hip/hip_runtime.h>
#include <hip/hip_bf16.h>
#include <stdint.h>

// ---------------------------------------------------------------------------
// LBConv: y = fc(relu(conv3x3_ternary(x))) + b
//   x        : [32][256][56][56] f32
//   binary_w : [512][256][3][3]  f32 (ternary)
//   fc_w     : [256][512]        f32
//   fc_b     : [256]             f32
//   out      : [32][256][56][56] f32
//
// R2 changes vs R1 (266us conv1, 665MB fetch, 528us total):
//  - XCD-contiguous block swizzle in conv1/conv2: xcd = id&7 owns a
//    contiguous ntile range so L2 absorbs Xp reuse (12 readers/row).
//  - k_xprep: thread handles full klo-group (8 cins, one w) -> 8 coalesced
//    f32 loads + single 16B store (was 1 elem/thread, stride-12KB lanes).
// ---------------------------------------------------------------------------

typedef __attribute__((ext_vector_type(8))) short short8;
typedef __attribute__((ext_vector_type(4))) float floatx4;

#define ROWE 8192            // elems per padded row per (b,cg): 16*64*8
#define NT_PER_B 28          // 3584/128

// workspace byte offsets
#define OFF_WP  0            // 9*2*512*128*2        = 2,359,296
#define OFF_A2  2359296      // 4*2*128*128*2        =   262,144
#define OFF_XP  2621440      // 64*58*8192*2         = 60,817,408
#define OFF_Y   63439872     // 896*4*16384*2        = 117,440,512
// total required ws: 180,880,384 bytes (~173 MB)

__device__ static inline void async16(const void* gptr, void* lptr) {
  __builtin_amdgcn_global_load_lds(
      (const __attribute__((address_space(1))) void*)gptr,
      (__attribute__((address_space(3))) void*)lptr,
      16, 0, 0);
}

__device__ static inline unsigned short f2bf(float x) {
  __hip_bfloat16 h = __float2bfloat16(x);
  return *reinterpret_cast<unsigned short*>(&h);
}

// ---------------- prep: x (NCHW f32) -> Xp[b*2+cg][h'58][khi16][w'64][klo8] bf16
// One thread per (bc,hp,khi,wq): reads 8 cins (wave-coalesced along w for
// each j), writes one 16B chunk. 3,801,088 threads / 256 = 14848 blocks.
__global__ void k_xprep(const float* __restrict__ x, __hip_bfloat16* __restrict__ Xp) {
  const int t = blockIdx.x * 256 + threadIdx.x;
  const int wq  = t & 63;
  const int khi = (t >> 6) & 15;
  const int t2  = t >> 10;                               // bc*58 + hp
  const int hp  = t2 % 58;
  const int bc  = t2 / 58;
  const int b   = bc >> 1;
  const int cin0 = ((bc & 1) << 7) + (khi << 3);
  const int h = hp - 1, w = wq - 1;
  unsigned short v[8];
  if ((unsigned)h < 56u && (unsigned)w < 56u) {
    const float* xp = x + ((size_t)(b * 256 + cin0) * 56 + h) * 56 + w;
#pragma unroll
    for (int j = 0; j < 8; ++j) v[j] = f2bf(xp[(size_t)j * 3136]);
  } else {
#pragma unroll
    for (int j = 0; j < 8; ++j) v[j] = 0;
  }
  uint4 pk;
  pk.x = (unsigned)v[0] | ((unsigned)v[1] << 16);
  pk.y = (unsigned)v[2] | ((unsigned)v[3] << 16);
  pk.z = (unsigned)v[4] | ((unsigned)v[5] << 16);
  pk.w = (unsigned)v[6] | ((unsigned)v[7] << 16);
  *(uint4*)(Xp + (size_t)t * 8) = pk;
}

// ---------------- prep: binary_w -> Wp[tap9][cg2][cmblk4][cmh2][khi16][cml64][klo8]
__global__ void k_wprep(const float* __restrict__ bw, __hip_bfloat16* __restrict__ Wp) {
  const int idx = blockIdx.x * 256 + threadIdx.x;        // < 1,179,648 exact
  const int klo = idx & 7;
  const int cml = (idx >> 3) & 63;
  const int khi = (idx >> 9) & 15;
  const int cmh = (idx >> 13) & 1;
  const int rest = idx >> 14;                            // (tap*2+cg)*4 + cmblk
  const int cmblk = rest & 3;
  const int tcg = rest >> 2;
  const int cg  = tcg & 1;
  const int tap = tcg >> 1;
  const int kh = tap / 3, kw = tap - kh * 3;
  const int cm  = (cmblk << 7) + (cmh << 6) + cml;
  const int cin = (cg << 7) + (khi << 3) + klo;
  Wp[idx] = __float2bfloat16(bw[((cm * 256 + cin) * 3 + kh) * 3 + kw]);
}

// ---------------- prep: fc_w -> A2[cg4][mtile2][ch2][khi16][cl64][klo8]
__global__ void k_a2prep(const float* __restrict__ fw, __hip_bfloat16* __restrict__ A2) {
  const int idx = blockIdx.x * 256 + threadIdx.x;        // < 131,072 exact
  const int klo = idx & 7;
  const int cl  = (idx >> 3) & 63;
  const int khi = (idx >> 9) & 15;
  const int ch  = (idx >> 13) & 1;
  const int rest = idx >> 14;                            // cg*2 + mtile
  const int mtile = rest & 1;
  const int cg = rest >> 1;
  const int cout = (mtile << 7) + (ch << 6) + cl;
  const int cm   = (cg << 7) + (khi << 3) + klo;
  A2[idx] = __float2bfloat16(fw[cout * 512 + cm]);
}

// ---------------- conv1: Y[ntile][cmblk][r2][khi16][w64][klo8] = relu(W*Xp)
// Grid: 3584 1-D. xcd = id&7 owns ntiles [xcd*112, xcd*112+112), cmblk
// fastest within xcd -> co-resident working set ~3.5MB fits 4MB XCD L2.
__global__ __launch_bounds__(256, 2) void k_conv1(
    const __hip_bfloat16* __restrict__ Xp, const __hip_bfloat16* __restrict__ Wp,
    __hip_bfloat16* __restrict__ Y) {
  __shared__ short8 lds_raw[4096];                       // 64KB: A[0,32K) B[32K,64K)
  char* lds = (char*)lds_raw;
  const int tid  = threadIdx.x;
  const int lane = tid & 63;
  const int wv   = tid >> 6;
  const int wm   = wv >> 1, wn = wv & 1;
  const int l15  = lane & 15;
  const int quad = lane >> 4;
  const int id   = blockIdx.x;
  const int xcd  = id & 7;
  const int seq  = id >> 3;                              // 0..447
  const int cmblk = seq & 3;
  const int ntile = xcd * 112 + (seq >> 2);              // 0..895
  const int b  = ntile / NT_PER_B;
  const int h0 = (ntile % NT_PER_B) * 2;

  floatx4 acc[4][4];
#pragma unroll
  for (int i = 0; i < 4; i++)
#pragma unroll
    for (int j = 0; j < 4; j++) acc[i][j] = (floatx4){0.f, 0.f, 0.f, 0.f};

  for (int t = 0; t < 18; ++t) {
    const int tap = t >> 1;
    const int cg  = t & 1;
    const int kh = tap / 3, kw = tap - kh * 3;
    const size_t a_base = (size_t)((tap * 2 + cg) * 4 + cmblk) * 16384;
    const size_t b_base = (size_t)((b * 2 + cg) * 58 + (h0 + kh)) * ROWE + kw * 8;
    __syncthreads();                                     // prev compute done
    const char* gA = (const char*)(Wp + a_base) + wv * 8192 + lane * 16;
    const char* gB = (const char*)(Xp + b_base) + wv * 8192 + lane * 16;
    char* lA = lds + wv * 8192;
    char* lB = lds + 32768 + wv * 8192;
#pragma unroll
    for (int c = 0; c < 8; ++c) {
      async16(gA + c * 1024, lA + c * 1024);
      async16(gB + c * 1024, lB + c * 1024);
    }
    __syncthreads();                                     // staging visible
#pragma unroll
    for (int kk = 0; kk < 4; ++kk) {
      short8 af[4], bf[4];
#pragma unroll
      for (int mi = 0; mi < 4; ++mi) {
        const int m = wm * 64 + mi * 16 + l15;
        af[mi] = *(const short8*)(lds + ((m >> 6) * 16 + kk * 4 + quad) * 1024 + (m & 63) * 16);
      }
#pragma unroll
      for (int ni = 0; ni < 4; ++ni) {
        const int n = wn * 64 + ni * 16 + l15;
        bf[ni] = *(const short8*)(lds + 32768 + ((n >> 6) * 16 + kk * 4 + quad) * 1024 + (n & 63) * 16);
      }
#pragma unroll
      for (int mi = 0; mi < 4; ++mi)
#pragma unroll
        for (int ni = 0; ni < 4; ++ni)
          acc[mi][ni] = __builtin_amdgcn_mfma_f32_16x16x32_bf16(af[mi], bf[ni], acc[mi][ni], 0, 0, 0);
    }
  }

  // epilogue: relu -> bf16, Y chunk (ntile, cmblk) layout [r2][khi16][w64][klo8]
  const size_t ybase = ((size_t)ntile * 4 + cmblk) * 16384;
#pragma unroll
  for (int mi = 0; mi < 4; ++mi) {
    const int cml  = wm * 64 + mi * 16 + quad * 4;       // + reg r
    const int khi  = cml >> 3;
    const int klo0 = cml & 7;                            // 0 or 4
#pragma unroll
    for (int ni = 0; ni < 4; ++ni) {
      const int n = wn * 64 + ni * 16 + l15;
      const int r = n >> 6, w = n & 63;
      floatx4 f = acc[mi][ni];
      unsigned lo = (unsigned)f2bf(fmaxf(f[0], 0.f)) | ((unsigned)f2bf(fmaxf(f[1], 0.f)) << 16);
      unsigned hi = (unsigned)f2bf(fmaxf(f[2], 0.f)) | ((unsigned)f2bf(fmaxf(f[3], 0.f)) << 16);
      uint2 pk = make_uint2(lo, hi);
      *(uint2*)((char*)Y + (ybase + (size_t)r * 8192 + khi * 512 + w * 8 + klo0) * 2) = pk;
    }
  }
}

// ---------------- conv2: out = fc_w * Y + b, mask w<56, store NCHW f32
// Grid: 1792 1-D. xcd = id&7 owns rp range; mtile fastest so both readers
// of each Y chunk land on the same XCD L2.
__global__ __launch_bounds__(256, 2) void k_conv2(
    const __hip_bfloat16* __restrict__ Y, const __hip_bfloat16* __restrict__ A2,
    const float* __restrict__ fcb, float* __restrict__ out) {
  __shared__ short8 lds_raw[4096];
  char* lds = (char*)lds_raw;
  const int tid  = threadIdx.x;
  const int lane = tid & 63;
  const int wv   = tid >> 6;
  const int wm   = wv >> 1, wn = wv & 1;
  const int l15  = lane & 15;
  const int quad = lane >> 4;
  const int id   = blockIdx.x;
  const int xcd  = id & 7;
  const int seq  = id >> 3;                              // 0..223
  const int mtile = seq & 1;
  const int rp    = xcd * 112 + (seq >> 1);              // 0..895

  floatx4 acc[4][4];
#pragma unroll
  for (int i = 0; i < 4; i++)
#pragma unroll
    for (int j = 0; j < 4; j++) acc[i][j] = (floatx4){0.f, 0.f, 0.f, 0.f};

  for (int cg = 0; cg < 4; ++cg) {
    const size_t a_base = (size_t)(cg * 2 + mtile) * 16384;
    const size_t b_base = (size_t)(rp * 4 + cg) * 16384;
    __syncthreads();
    const char* gA = (const char*)(A2 + a_base) + wv * 8192 + lane * 16;
    const char* gB = (const char*)(Y + b_base) + wv * 8192 + lane * 16;
    char* lA = lds + wv * 8192;
    char* lB = lds + 32768 + wv * 8192;
#pragma unroll
    for (int c = 0; c < 8; ++c) {
      async16(gA + c * 1024, lA + c * 1024);
      async16(gB + c * 1024, lB + c * 1024);
    }
    __syncthreads();
#pragma unroll
    for (int kk = 0; kk < 4; ++kk) {
      short8 af[4], bf[4];
#pragma unroll
      for (int mi = 0; mi < 4; ++mi) {
        const int m = wm * 64 + mi * 16 + l15;
        af[mi] = *(const short8*)(lds + ((m >> 6) * 16 + kk * 4 + quad) * 1024 + (m & 63) * 16);
      }
#pragma unroll
      for (int ni = 0; ni < 4; ++ni) {
        const int n = wn * 64 + ni * 16 + l15;
        bf[ni] = *(const short8*)(lds + 32768 + ((n >> 6) * 16 + kk * 4 + quad) * 1024 + (n & 63) * 16);
      }
#pragma unroll
      for (int mi = 0; mi < 4; ++mi)
#pragma unroll
        for (int ni = 0; ni < 4; ++ni)
          acc[mi][ni] = __builtin_amdgcn_mfma_f32_16x16x32_bf16(af[mi], bf[ni], acc[mi][ni], 0, 0, 0);
    }
  }

  const int b   = rp / NT_PER_B;
  const int nb0 = (rp % NT_PER_B) * 128;
#pragma unroll
  for (int mi = 0; mi < 4; ++mi) {
    const int co = mtile * 128 + wm * 64 + mi * 16 + quad * 4;  // + reg r
#pragma unroll
    for (int ni = 0; ni < 4; ++ni) {
      const int n = wn * 64 + ni * 16 + l15;
      const int w = n & 63;
      if (w < 56) {
        const int nb = nb0 + n;
        const int h  = nb >> 6;
        floatx4 f = acc[mi][ni];
        const size_t base = (size_t)(b * 256 + co) * 3136 + h * 56 + w;
#pragma unroll
        for (int r = 0; r < 4; ++r)
          out[base + (size_t)r * 3136] = f[r] + fcb[co + r];
      }
    }
  }
}

extern "C" void kernel_launch(void* const* d_in, const int* in_sizes, int n_in,
                              void* d_out, int out_size, void* d_ws, size_t ws_size,
                              hipStream_t stream) {
  const float* x  = (const float*)d_in[0];
  const float* bw = (const float*)d_in[1];
  const float* fw = (const float*)d_in[2];
  const float* fb = (const float*)d_in[3];
  float* out = (float*)d_out;
  char* ws = (char*)d_ws;

  __hip_bfloat16* Wp = (__hip_bfloat16*)(ws + OFF_WP);
  __hip_bfloat16* A2 = (__hip_bfloat16*)(ws + OFF_A2);
  __hip_bfloat16* Xp = (__hip_bfloat16*)(ws + OFF_XP);
  __hip_bfloat16* Y  = (__hip_bfloat16*)(ws + OFF_Y);

  k_wprep<<<dim3(4608), dim3(256), 0, stream>>>(bw, Wp);
  k_a2prep<<<dim3(512), dim3(256), 0, stream>>>(fw, A2);
  k_xprep<<<dim3(14848), dim3(256), 0, stream>>>(x, Xp);
  k_conv1<<<dim3(3584), dim3(256), 0, stream>>>(Xp, Wp, Y);
  k_conv2<<<dim3(1792), dim3(256), 0, stream>>>(Y, A2, fb, out);
}